// Round 18
// baseline (3485.343 us; speedup 1.0000x reference)
//
#include <hip/hip_runtime.h>
#include <math.h>

#define N_ATOMS 50000
#define D 32
#define E_EDGES 300000
#define BD 16
#define SW 544                                // 17*32 (16 bond ch + 1 bias ch)
#define PADN 50176                            // 196*256
#define SCAN_BLOCKS 196
#define GRU_TILE 8
#define GRU_NT (N_ATOMS / GRU_TILE)           // 6250

#define NB 32                                 // src nodes per block (4 per half-wave)
#define FBLOCKS ((N_ATOMS + NB - 1) / NB)     // 1563
#define WHALF (16 * SW / 4)                   // 2176 float4 per W half-tile

__device__ __forceinline__ float sigmoidf_(float x) {
    return 1.0f / (1.0f + __expf(-x));
}

// ---------- precompute (once per launch) ----------

// WTj[j*544 + b*32 + i] = W[b,i,j]  (b<16: kernel.reshape(16,32,32); b=16: Bm)
__global__ void k_build_wt(const float* __restrict__ kern,
                           const float* __restrict__ bias,
                           float* __restrict__ WTj) {
    int idx = blockIdx.x * 256 + threadIdx.x;
    if (idx >= 32 * SW) return;
    int j = idx / SW;
    int r = idx - j * SW;
    int b = r >> 5, i = r & 31;
    WTj[idx] = (b < BD) ? kern[b * 1024 + i * 32 + j] : bias[i * 32 + j];
}

// CSR by SRC (pair[:,1])
__global__ void k_hist(const int* __restrict__ pair, int* __restrict__ deg) {
    int e = blockIdx.x * 256 + threadIdx.x;
    if (e < E_EDGES) atomicAdd(&deg[pair[2 * e + 1]], 1);
}

__global__ void k_scan1(const int* __restrict__ deg, int* __restrict__ offs,
                        int* __restrict__ bsums) {
    __shared__ int sm[256];
    int t = threadIdx.x, gid = blockIdx.x * 256 + t;
    int v = deg[gid];                 // deg[50000..PADN) is zeroed
    sm[t] = v;
    __syncthreads();
    for (int off = 1; off < 256; off <<= 1) {
        int x = (t >= off) ? sm[t - off] : 0;
        __syncthreads();
        sm[t] += x;
        __syncthreads();
    }
    offs[gid] = sm[t] - v;
    if (t == 255) bsums[blockIdx.x] = sm[255];
}

__global__ void k_scan2(const int* __restrict__ bsums, int* __restrict__ boffs, int nb) {
    __shared__ int sm[256];
    int t = threadIdx.x;
    int v = (t < nb) ? bsums[t] : 0;
    sm[t] = v;
    __syncthreads();
    for (int off = 1; off < 256; off <<= 1) {
        int x = (t >= off) ? sm[t - off] : 0;
        __syncthreads();
        sm[t] += x;
        __syncthreads();
    }
    if (t < nb) boffs[t] = sm[t] - v;
}

__global__ void k_scan3(int* __restrict__ offs, const int* __restrict__ boffs) {
    int gid = blockIdx.x * 256 + threadIdx.x;
    offs[gid] += boffs[blockIdx.x];
}

// Permute edges to src-CSR order; materialize bond rows and dst in that order.
__global__ void k_scatter_perm(const int* __restrict__ pair, const int* __restrict__ offs,
                               int* __restrict__ cursor, const float* __restrict__ bond,
                               float* __restrict__ bond_perm, int* __restrict__ dstid) {
    int e = blockIdx.x * 256 + threadIdx.x;
    if (e >= E_EDGES) return;
    int d = pair[2 * e], s = pair[2 * e + 1];
    int pos = offs[s] + atomicAdd(&cursor[s], 1);
    dstid[pos] = d;
    const float4* src4 = (const float4*)(bond + (size_t)e * BD);
    float4* dst4 = (float4*)(bond_perm + (size_t)pos * BD);
    dst4[0] = src4[0];
    dst4[1] = src4[1];
    dst4[2] = src4[2];
    dst4[3] = src4[3];
}

#define EDGE_FMA(M, B0, B1, B2, B3, YN) do {            \
    M = fmaf(B0.x, YN[0],  M); M = fmaf(B0.y, YN[1],  M); \
    M = fmaf(B0.z, YN[2],  M); M = fmaf(B0.w, YN[3],  M); \
    M = fmaf(B1.x, YN[4],  M); M = fmaf(B1.y, YN[5],  M); \
    M = fmaf(B1.z, YN[6],  M); M = fmaf(B1.w, YN[7],  M); \
    M = fmaf(B2.x, YN[8],  M); M = fmaf(B2.y, YN[9],  M); \
    M = fmaf(B2.z, YN[10], M); M = fmaf(B2.w, YN[11], M); \
    M = fmaf(B3.x, YN[12], M); M = fmaf(B3.y, YN[13], M); \
    M = fmaf(B3.z, YN[14], M); M = fmaf(B3.w, YN[15], M); \
} while (0)

// ---------- fused projection + edge kernel (W staged in LDS, 2 halves) ----------
// Phase A previously issued 544 scalar L2 loads per thread (~200cyc each) with
// only 2 waves/SIMD to cover them -- the ~20us/batch stall. Now W is staged
// per 16-j half into LDS (34.8KB; 2176 float4 coalesced loads spread over the
// block), and Phase A reads W via conflict-free LDS (lanes 0-31 banks 0-31,
// lanes 32-63 same-addr broadcast). LDS total 39KB -> 4 blocks/CU.
__global__ __launch_bounds__(256, 4)
void k_fused(const float* __restrict__ h_in, float* __restrict__ agg,
             const float* __restrict__ bond_perm, const int* __restrict__ dstid,
             const float* __restrict__ WTj,
             const int* __restrict__ offs, const int* __restrict__ deg) {
    __shared__ float Wlds[16 * SW];       // 34816 B (one 16-j half of W)
    __shared__ float h_lds[NB][33];       //  4224 B  -> 39040 B total

    const int t = threadIdx.x;
    const int bbase = blockIdx.x * NB;
    const int i = t & 31;                 // feature lane
    const int grp = t >> 5;               // half-wave 0..7
    const int hn0 = grp * 4;

    // ---- stage W half 0 (coalesced float4) + h tile
    {
        const float4* Wg = (const float4*)WTj;
        float4* Wl = (float4*)Wlds;
#pragma unroll
        for (int k = 0; k < 9; ++k) {     // 2176 = 8*256 + 128
            const int c = t + 256 * k;
            if (c < WHALF) Wl[c] = Wg[c];
        }
    }
#pragma unroll
    for (int k = 0; k < 4; ++k) {
        const int idx = t + 256 * k;
        const int n = idx >> 5, j = idx & 31;
        const int node = bbase + n;
        h_lds[n][j] = (node < N_ATOMS) ? h_in[(size_t)node * D + j] : 0.f;
    }

    int stv[4], env[4];
#pragma unroll
    for (int n = 0; n < 4; ++n) {
        const int node = bbase + hn0 + n;
        const bool ok = (node < N_ATOMS);
        const int o = ok ? offs[node] : 0;
        stv[n] = o;
        env[n] = o + (ok ? deg[node] : 0);
    }
    __syncthreads();

    // ---- Phase A: y[n][b] = sum_j W[j][b*32+i] * h[node_n][j], W from LDS
    float y[4][17];
#pragma unroll
    for (int n = 0; n < 4; ++n)
#pragma unroll
        for (int b = 0; b < 17; ++b) y[n][b] = 0.f;

#pragma unroll
    for (int half = 0; half < 2; ++half) {
        if (half) {                       // restage second 16-j half
            __syncthreads();              // everyone done reading half 0
            const float4* Wg = (const float4*)WTj;
            float4* Wl = (float4*)Wlds;
#pragma unroll
            for (int k = 0; k < 9; ++k) {
                const int c = t + 256 * k;
                if (c < WHALF) Wl[c] = Wg[WHALF + c];
            }
            __syncthreads();              // staging visible
        }
        const int j0 = half * 16;
        for (int jl = 0; jl < 16; ++jl) { // not unrolled: bounds VGPR
            const float* wrow = &Wlds[jl * SW + i];
            float wv[17];
#pragma unroll
            for (int b = 0; b < 17; ++b)
                wv[b] = wrow[b * 32];     // LDS, conflict-free
#pragma unroll
            for (int n = 0; n < 4; ++n) {
                const float hv = h_lds[hn0 + n][j0 + jl];
#pragma unroll
                for (int b = 0; b < 17; ++b)
                    y[n][b] = fmaf(wv[b], hv, y[n][b]);
            }
        }
    }

    // ---- Phase B: linear streams in, fire-and-forget atomics out
#pragma unroll
    for (int n = 0; n < 4; ++n) {
        int p = stv[n];
        const int e = env[n];
        for (; p + 2 <= e; p += 2) {
            const float4* bp0 = (const float4*)(bond_perm + (size_t)p * BD);
            const float4* bp1 = (const float4*)(bond_perm + (size_t)(p + 1) * BD);
            const int d0 = dstid[p];
            const int d1 = dstid[p + 1];
            const float4 a0 = bp0[0], a1 = bp0[1], a2 = bp0[2], a3 = bp0[3];
            const float4 c0 = bp1[0], c1 = bp1[1], c2 = bp1[2], c3 = bp1[3];
            float m0 = y[n][16];          // bias channel (bond == 1)
            float m1 = y[n][16];
            EDGE_FMA(m0, a0, a1, a2, a3, y[n]);
            EDGE_FMA(m1, c0, c1, c2, c3, y[n]);
            atomicAdd(&agg[(size_t)d0 * D + i], m0);
            atomicAdd(&agg[(size_t)d1 * D + i], m1);
        }
        if (p < e) {
            const float4* bp0 = (const float4*)(bond_perm + (size_t)p * BD);
            const int d0 = dstid[p];
            const float4 a0 = bp0[0], a1 = bp0[1], a2 = bp0[2], a3 = bp0[3];
            float m0 = y[n][16];
            EDGE_FMA(m0, a0, a1, a2, a3, y[n]);
            atomicAdd(&agg[(size_t)d0 * D + i], m0);
        }
    }
}

// ---------- GRU kernel: h_out = GRUCell(agg, h_in); zeroes agg after read ----------
__global__ __launch_bounds__(256, 2)
void k_gru(float* __restrict__ agg_g, const float* __restrict__ h_in,
           float* __restrict__ h_out,
           const float* __restrict__ Wih, const float* __restrict__ Whh,
           const float* __restrict__ bih, const float* __restrict__ bhh) {
    __shared__ float Wih_s[96][33];
    __shared__ float Whh_s[96][33];
    __shared__ float bih_s[96], bhh_s[96];
    __shared__ float x_lds[GRU_TILE][32];
    __shared__ float h_lds[GRU_TILE][32];

    const int t = threadIdx.x;

    for (int idx = t; idx < 96 * 32; idx += 256) {
        const int o = idx >> 5, jj = idx & 31;
        Wih_s[o][jj] = Wih[idx];
        Whh_s[o][jj] = Whh[idx];
    }
    if (t < 96) { bih_s[t] = bih[t]; bhh_s[t] = bhh[t]; }

    const int r = t >> 5;
    const int i = t & 31;
    const int stride = gridDim.x;

    int tile = blockIdx.x;
    float xr = 0.f, hr = 0.f;
    if (tile < GRU_NT) {
        xr = agg_g[tile * 256 + t];
        hr = h_in[tile * 256 + t];
    }
    for (; tile < GRU_NT; tile += stride) {
        ((float*)x_lds)[t] = xr;
        ((float*)h_lds)[t] = hr;
        agg_g[tile * 256 + t] = 0.f;      // consumed -> zero for next step
        __syncthreads();
        const int nxt = tile + stride;
        if (nxt < GRU_NT) {               // prefetch next tile during compute
            xr = agg_g[nxt * 256 + t];
            hr = h_in[nxt * 256 + t];
        }
        float gri = bih_s[i],      grh = bhh_s[i];
        float gzi = bih_s[32 + i], gzh = bhh_s[32 + i];
        float gni = bih_s[64 + i], gnh = bhh_s[64 + i];
#pragma unroll 8
        for (int jj = 0; jj < 32; ++jj) {
            const float xv = x_lds[r][jj];
            const float hv = h_lds[r][jj];
            gri = fmaf(Wih_s[i][jj],      xv, gri);
            gzi = fmaf(Wih_s[32 + i][jj], xv, gzi);
            gni = fmaf(Wih_s[64 + i][jj], xv, gni);
            grh = fmaf(Whh_s[i][jj],      hv, grh);
            gzh = fmaf(Whh_s[32 + i][jj], hv, gzh);
            gnh = fmaf(Whh_s[64 + i][jj], hv, gnh);
        }
        const float rg = sigmoidf_(gri + grh);
        const float zg = sigmoidf_(gzi + gzh);
        float xn = gni + rg * gnh;
        xn = fminf(fmaxf(xn, -15.f), 15.f);
        const float e2 = __expf(2.f * xn);
        const float ng = (e2 - 1.f) / (e2 + 1.f);
        h_out[tile * 256 + t] = (1.f - zg) * ng + zg * h_lds[r][i];
        __syncthreads();
    }
}

// ---------- launch ----------
extern "C" void kernel_launch(void* const* d_in, const int* in_sizes, int n_in,
                              void* d_out, int out_size, void* d_ws, size_t ws_size,
                              hipStream_t stream) {
    const float* atom = (const float*)d_in[0];
    const float* bond = (const float*)d_in[1];
    const int*   pair = (const int*)d_in[2];
    const float* kern = (const float*)d_in[3];
    const float* bias = (const float*)d_in[4];
    const float* Wih  = (const float*)d_in[5];
    const float* Whh  = (const float*)d_in[6];
    const float* bih  = (const float*)d_in[7];
    const float* bhh  = (const float*)d_in[8];
    float* out = (float*)d_out;

    char* w = (char*)d_ws;
    auto alloc = [&](size_t bytes) {
        char* p = w;
        w += (bytes + 255) & ~size_t(255);
        return p;
    };
    float* hA        = (float*)alloc((size_t)N_ATOMS * D * 4);
    float* aggG      = (float*)alloc((size_t)N_ATOMS * D * 4);
    float* WTj       = (float*)alloc((size_t)32 * SW * 4);
    int*   degcur    = (int*)alloc((size_t)2 * PADN * 4);   // deg | cursor
    int*   offs      = (int*)alloc((size_t)PADN * 4);
    int*   bsums     = (int*)alloc(256 * 4);
    int*   boffs     = (int*)alloc(256 * 4);
    int*   dstid     = (int*)alloc((size_t)E_EDGES * 4);
    float* bond_perm = (float*)alloc((size_t)E_EDGES * BD * 4);
    int* deg    = degcur;
    int* cursor = degcur + PADN;

    hipMemsetAsync(degcur, 0, (size_t)2 * PADN * 4, stream);
    hipMemsetAsync(aggG, 0, (size_t)N_ATOMS * D * 4, stream);  // k_gru re-zeroes thereafter

    k_build_wt<<<(32 * SW + 255) / 256, 256, 0, stream>>>(kern, bias, WTj);
    k_hist<<<(E_EDGES + 255) / 256, 256, 0, stream>>>(pair, deg);
    k_scan1<<<SCAN_BLOCKS, 256, 0, stream>>>(deg, offs, bsums);
    k_scan2<<<1, 256, 0, stream>>>(bsums, boffs, SCAN_BLOCKS);
    k_scan3<<<SCAN_BLOCKS, 256, 0, stream>>>(offs, boffs);
    k_scatter_perm<<<(E_EDGES + 255) / 256, 256, 0, stream>>>(pair, offs, cursor,
                                                              bond, bond_perm, dstid);

    const float* hsrc = atom;
    float* hdst[4] = { hA, out, hA, out };
    for (int s = 0; s < 4; ++s) {
        k_fused<<<FBLOCKS, 256, 0, stream>>>(hsrc, aggG, bond_perm, dstid,
                                             WTj, offs, deg);
        k_gru<<<1024, 256, 0, stream>>>(aggG, hsrc, hdst[s], Wih, Whh, bih, bhh);
        hsrc = hdst[s];
    }
}

// Round 19
// 2268.959 us; speedup vs baseline: 1.5361x; 1.5361x over previous
//
#include <hip/hip_runtime.h>
#include <math.h>

#define N_ATOMS 50000
#define D 32
#define E_EDGES 300000
#define BD 16
#define SW 544                                // 17*32 (16 bond ch + 1 bias ch)
#define PADN 50176                            // 196*256
#define SCAN_BLOCKS 196
#define GRU_TILE 8
#define GRU_NT (N_ATOMS / GRU_TILE)           // 6250

#define NB 32                                 // src nodes per block (4 per half-wave)
#define FBLOCKS ((N_ATOMS + NB - 1) / NB)     // 1563
#define WHALF (16 * SW / 4)                   // 2176 float4 per W half-tile

__device__ __forceinline__ float sigmoidf_(float x) {
    return 1.0f / (1.0f + __expf(-x));
}

// ---------- precompute (once per launch) ----------

// WTj[j*544 + b*32 + i] = W[b,i,j]  (b<16: kernel.reshape(16,32,32); b=16: Bm)
__global__ void k_build_wt(const float* __restrict__ kern,
                           const float* __restrict__ bias,
                           float* __restrict__ WTj) {
    int idx = blockIdx.x * 256 + threadIdx.x;
    if (idx >= 32 * SW) return;
    int j = idx / SW;
    int r = idx - j * SW;
    int b = r >> 5, i = r & 31;
    WTj[idx] = (b < BD) ? kern[b * 1024 + i * 32 + j] : bias[i * 32 + j];
}

// CSR by SRC (pair[:,1])
__global__ void k_hist(const int* __restrict__ pair, int* __restrict__ deg) {
    int e = blockIdx.x * 256 + threadIdx.x;
    if (e < E_EDGES) atomicAdd(&deg[pair[2 * e + 1]], 1);
}

__global__ void k_scan1(const int* __restrict__ deg, int* __restrict__ offs,
                        int* __restrict__ bsums) {
    __shared__ int sm[256];
    int t = threadIdx.x, gid = blockIdx.x * 256 + t;
    int v = deg[gid];                 // deg[50000..PADN) is zeroed
    sm[t] = v;
    __syncthreads();
    for (int off = 1; off < 256; off <<= 1) {
        int x = (t >= off) ? sm[t - off] : 0;
        __syncthreads();
        sm[t] += x;
        __syncthreads();
    }
    offs[gid] = sm[t] - v;
    if (t == 255) bsums[blockIdx.x] = sm[255];
}

__global__ void k_scan2(const int* __restrict__ bsums, int* __restrict__ boffs, int nb) {
    __shared__ int sm[256];
    int t = threadIdx.x;
    int v = (t < nb) ? bsums[t] : 0;
    sm[t] = v;
    __syncthreads();
    for (int off = 1; off < 256; off <<= 1) {
        int x = (t >= off) ? sm[t - off] : 0;
        __syncthreads();
        sm[t] += x;
        __syncthreads();
    }
    if (t < nb) boffs[t] = sm[t] - v;
}

__global__ void k_scan3(int* __restrict__ offs, const int* __restrict__ boffs) {
    int gid = blockIdx.x * 256 + threadIdx.x;
    offs[gid] += boffs[blockIdx.x];
}

// Permute edges to src-CSR order; materialize bond rows and dst in that order.
__global__ void k_scatter_perm(const int* __restrict__ pair, const int* __restrict__ offs,
                               int* __restrict__ cursor, const float* __restrict__ bond,
                               float* __restrict__ bond_perm, int* __restrict__ dstid) {
    int e = blockIdx.x * 256 + threadIdx.x;
    if (e >= E_EDGES) return;
    int d = pair[2 * e], s = pair[2 * e + 1];
    int pos = offs[s] + atomicAdd(&cursor[s], 1);
    dstid[pos] = d;
    const float4* src4 = (const float4*)(bond + (size_t)e * BD);
    float4* dst4 = (float4*)(bond_perm + (size_t)pos * BD);
    dst4[0] = src4[0];
    dst4[1] = src4[1];
    dst4[2] = src4[2];
    dst4[3] = src4[3];
}

#define EDGE_FMA(M, B0, B1, B2, B3, YN) do {            \
    M = fmaf(B0.x, YN[0],  M); M = fmaf(B0.y, YN[1],  M); \
    M = fmaf(B0.z, YN[2],  M); M = fmaf(B0.w, YN[3],  M); \
    M = fmaf(B1.x, YN[4],  M); M = fmaf(B1.y, YN[5],  M); \
    M = fmaf(B1.z, YN[6],  M); M = fmaf(B1.w, YN[7],  M); \
    M = fmaf(B2.x, YN[8],  M); M = fmaf(B2.y, YN[9],  M); \
    M = fmaf(B2.z, YN[10], M); M = fmaf(B2.w, YN[11], M); \
    M = fmaf(B3.x, YN[12], M); M = fmaf(B3.y, YN[13], M); \
    M = fmaf(B3.z, YN[14], M); M = fmaf(B3.w, YN[15], M); \
} while (0)

// ---------- fused projection + edge kernel (W staged in LDS, 2 halves) ----------
// SAME experiment as r18 but with __launch_bounds__(256,2): r18's (256,4)
// pinned the allocator to 64 VGPR and spilled y[4][17] (WRITE 1.29 GB).
// (256,2) is the session-proven no-spill config for this body (r9/r17: 68-72
// VGPR). LDS 39KB still permits 4 blocks/CU, so occupancy is LDS-set (~50%)
// while W reads come from LDS instead of 544 serial L2 loads per thread.
__global__ __launch_bounds__(256, 2)
void k_fused(const float* __restrict__ h_in, float* __restrict__ agg,
             const float* __restrict__ bond_perm, const int* __restrict__ dstid,
             const float* __restrict__ WTj,
             const int* __restrict__ offs, const int* __restrict__ deg) {
    __shared__ float Wlds[16 * SW];       // 34816 B (one 16-j half of W)
    __shared__ float h_lds[NB][33];       //  4224 B  -> 39040 B total

    const int t = threadIdx.x;
    const int bbase = blockIdx.x * NB;
    const int i = t & 31;                 // feature lane
    const int grp = t >> 5;               // half-wave 0..7
    const int hn0 = grp * 4;

    // ---- stage W half 0 (coalesced float4) + h tile
    {
        const float4* Wg = (const float4*)WTj;
        float4* Wl = (float4*)Wlds;
#pragma unroll
        for (int k = 0; k < 9; ++k) {     // 2176 = 8*256 + 128
            const int c = t + 256 * k;
            if (c < WHALF) Wl[c] = Wg[c];
        }
    }
#pragma unroll
    for (int k = 0; k < 4; ++k) {
        const int idx = t + 256 * k;
        const int n = idx >> 5, j = idx & 31;
        const int node = bbase + n;
        h_lds[n][j] = (node < N_ATOMS) ? h_in[(size_t)node * D + j] : 0.f;
    }

    int stv[4], env[4];
#pragma unroll
    for (int n = 0; n < 4; ++n) {
        const int node = bbase + hn0 + n;
        const bool ok = (node < N_ATOMS);
        const int o = ok ? offs[node] : 0;
        stv[n] = o;
        env[n] = o + (ok ? deg[node] : 0);
    }
    __syncthreads();

    // ---- Phase A: y[n][b] = sum_j W[j][b*32+i] * h[node_n][j], W from LDS
    float y[4][17];
#pragma unroll
    for (int n = 0; n < 4; ++n)
#pragma unroll
        for (int b = 0; b < 17; ++b) y[n][b] = 0.f;

#pragma unroll
    for (int half = 0; half < 2; ++half) {
        if (half) {                       // restage second 16-j half
            __syncthreads();              // everyone done reading half 0
            const float4* Wg = (const float4*)WTj;
            float4* Wl = (float4*)Wlds;
#pragma unroll
            for (int k = 0; k < 9; ++k) {
                const int c = t + 256 * k;
                if (c < WHALF) Wl[c] = Wg[WHALF + c];
            }
            __syncthreads();              // staging visible
        }
        const int j0 = half * 16;
        for (int jl = 0; jl < 16; ++jl) { // not unrolled: bounds VGPR
            const float* wrow = &Wlds[jl * SW + i];
            float wv[17];
#pragma unroll
            for (int b = 0; b < 17; ++b)
                wv[b] = wrow[b * 32];     // LDS, conflict-free
#pragma unroll
            for (int n = 0; n < 4; ++n) {
                const float hv = h_lds[hn0 + n][j0 + jl];
#pragma unroll
                for (int b = 0; b < 17; ++b)
                    y[n][b] = fmaf(wv[b], hv, y[n][b]);
            }
        }
    }

    // ---- Phase B: linear streams in, fire-and-forget atomics out
#pragma unroll
    for (int n = 0; n < 4; ++n) {
        int p = stv[n];
        const int e = env[n];
        for (; p + 2 <= e; p += 2) {
            const float4* bp0 = (const float4*)(bond_perm + (size_t)p * BD);
            const float4* bp1 = (const float4*)(bond_perm + (size_t)(p + 1) * BD);
            const int d0 = dstid[p];
            const int d1 = dstid[p + 1];
            const float4 a0 = bp0[0], a1 = bp0[1], a2 = bp0[2], a3 = bp0[3];
            const float4 c0 = bp1[0], c1 = bp1[1], c2 = bp1[2], c3 = bp1[3];
            float m0 = y[n][16];          // bias channel (bond == 1)
            float m1 = y[n][16];
            EDGE_FMA(m0, a0, a1, a2, a3, y[n]);
            EDGE_FMA(m1, c0, c1, c2, c3, y[n]);
            atomicAdd(&agg[(size_t)d0 * D + i], m0);
            atomicAdd(&agg[(size_t)d1 * D + i], m1);
        }
        if (p < e) {
            const float4* bp0 = (const float4*)(bond_perm + (size_t)p * BD);
            const int d0 = dstid[p];
            const float4 a0 = bp0[0], a1 = bp0[1], a2 = bp0[2], a3 = bp0[3];
            float m0 = y[n][16];
            EDGE_FMA(m0, a0, a1, a2, a3, y[n]);
            atomicAdd(&agg[(size_t)d0 * D + i], m0);
        }
    }
}

// ---------- GRU kernel: h_out = GRUCell(agg, h_in); zeroes agg after read ----------
__global__ __launch_bounds__(256, 2)
void k_gru(float* __restrict__ agg_g, const float* __restrict__ h_in,
           float* __restrict__ h_out,
           const float* __restrict__ Wih, const float* __restrict__ Whh,
           const float* __restrict__ bih, const float* __restrict__ bhh) {
    __shared__ float Wih_s[96][33];
    __shared__ float Whh_s[96][33];
    __shared__ float bih_s[96], bhh_s[96];
    __shared__ float x_lds[GRU_TILE][32];
    __shared__ float h_lds[GRU_TILE][32];

    const int t = threadIdx.x;

    for (int idx = t; idx < 96 * 32; idx += 256) {
        const int o = idx >> 5, jj = idx & 31;
        Wih_s[o][jj] = Wih[idx];
        Whh_s[o][jj] = Whh[idx];
    }
    if (t < 96) { bih_s[t] = bih[t]; bhh_s[t] = bhh[t]; }

    const int r = t >> 5;
    const int i = t & 31;
    const int stride = gridDim.x;

    int tile = blockIdx.x;
    float xr = 0.f, hr = 0.f;
    if (tile < GRU_NT) {
        xr = agg_g[tile * 256 + t];
        hr = h_in[tile * 256 + t];
    }
    for (; tile < GRU_NT; tile += stride) {
        ((float*)x_lds)[t] = xr;
        ((float*)h_lds)[t] = hr;
        agg_g[tile * 256 + t] = 0.f;      // consumed -> zero for next step
        __syncthreads();
        const int nxt = tile + stride;
        if (nxt < GRU_NT) {               // prefetch next tile during compute
            xr = agg_g[nxt * 256 + t];
            hr = h_in[nxt * 256 + t];
        }
        float gri = bih_s[i],      grh = bhh_s[i];
        float gzi = bih_s[32 + i], gzh = bhh_s[32 + i];
        float gni = bih_s[64 + i], gnh = bhh_s[64 + i];
#pragma unroll 8
        for (int jj = 0; jj < 32; ++jj) {
            const float xv = x_lds[r][jj];
            const float hv = h_lds[r][jj];
            gri = fmaf(Wih_s[i][jj],      xv, gri);
            gzi = fmaf(Wih_s[32 + i][jj], xv, gzi);
            gni = fmaf(Wih_s[64 + i][jj], xv, gni);
            grh = fmaf(Whh_s[i][jj],      hv, grh);
            gzh = fmaf(Whh_s[32 + i][jj], hv, gzh);
            gnh = fmaf(Whh_s[64 + i][jj], hv, gnh);
        }
        const float rg = sigmoidf_(gri + grh);
        const float zg = sigmoidf_(gzi + gzh);
        float xn = gni + rg * gnh;
        xn = fminf(fmaxf(xn, -15.f), 15.f);
        const float e2 = __expf(2.f * xn);
        const float ng = (e2 - 1.f) / (e2 + 1.f);
        h_out[tile * 256 + t] = (1.f - zg) * ng + zg * h_lds[r][i];
        __syncthreads();
    }
}

// ---------- launch ----------
extern "C" void kernel_launch(void* const* d_in, const int* in_sizes, int n_in,
                              void* d_out, int out_size, void* d_ws, size_t ws_size,
                              hipStream_t stream) {
    const float* atom = (const float*)d_in[0];
    const float* bond = (const float*)d_in[1];
    const int*   pair = (const int*)d_in[2];
    const float* kern = (const float*)d_in[3];
    const float* bias = (const float*)d_in[4];
    const float* Wih  = (const float*)d_in[5];
    const float* Whh  = (const float*)d_in[6];
    const float* bih  = (const float*)d_in[7];
    const float* bhh  = (const float*)d_in[8];
    float* out = (float*)d_out;

    char* w = (char*)d_ws;
    auto alloc = [&](size_t bytes) {
        char* p = w;
        w += (bytes + 255) & ~size_t(255);
        return p;
    };
    float* hA        = (float*)alloc((size_t)N_ATOMS * D * 4);
    float* aggG      = (float*)alloc((size_t)N_ATOMS * D * 4);
    float* WTj       = (float*)alloc((size_t)32 * SW * 4);
    int*   degcur    = (int*)alloc((size_t)2 * PADN * 4);   // deg | cursor
    int*   offs      = (int*)alloc((size_t)PADN * 4);
    int*   bsums     = (int*)alloc(256 * 4);
    int*   boffs     = (int*)alloc(256 * 4);
    int*   dstid     = (int*)alloc((size_t)E_EDGES * 4);
    float* bond_perm = (float*)alloc((size_t)E_EDGES * BD * 4);
    int* deg    = degcur;
    int* cursor = degcur + PADN;

    hipMemsetAsync(degcur, 0, (size_t)2 * PADN * 4, stream);
    hipMemsetAsync(aggG, 0, (size_t)N_ATOMS * D * 4, stream);  // k_gru re-zeroes thereafter

    k_build_wt<<<(32 * SW + 255) / 256, 256, 0, stream>>>(kern, bias, WTj);
    k_hist<<<(E_EDGES + 255) / 256, 256, 0, stream>>>(pair, deg);
    k_scan1<<<SCAN_BLOCKS, 256, 0, stream>>>(deg, offs, bsums);
    k_scan2<<<1, 256, 0, stream>>>(bsums, boffs, SCAN_BLOCKS);
    k_scan3<<<SCAN_BLOCKS, 256, 0, stream>>>(offs, boffs);
    k_scatter_perm<<<(E_EDGES + 255) / 256, 256, 0, stream>>>(pair, offs, cursor,
                                                              bond, bond_perm, dstid);

    const float* hsrc = atom;
    float* hdst[4] = { hA, out, hA, out };
    for (int s = 0; s < 4; ++s) {
        k_fused<<<FBLOCKS, 256, 0, stream>>>(hsrc, aggG, bond_perm, dstid,
                                             WTj, offs, deg);
        k_gru<<<1024, 256, 0, stream>>>(aggG, hsrc, hdst[s], Wih, Whh, bih, bhh);
        hsrc = hdst[s];
    }
}

// Round 20
// 480.265 us; speedup vs baseline: 7.2571x; 4.7244x over previous
//
#include <hip/hip_runtime.h>
#include <math.h>

#define N_ATOMS 50000
#define D 32
#define E_EDGES 300000
#define BD 16
#define SW 544                                // 17*32 (16 bond ch + 1 bias ch)
#define PADN 50176                            // 196*256
#define SCAN_BLOCKS 196
#define GRU_TILE 8
#define GRU_NT (N_ATOMS / GRU_TILE)           // 6250

#define NB 32                                 // src nodes per block (4 per half-wave)
#define FBLOCKS ((N_ATOMS + NB - 1) / NB)     // 1563

__device__ __forceinline__ float sigmoidf_(float x) {
    return 1.0f / (1.0f + __expf(-x));
}

// ---------- precompute (once per launch) ----------

// WTj[j*544 + b*32 + i] = W[b,i,j]  (b<16: kernel.reshape(16,32,32); b=16: Bm)
__global__ void k_build_wt(const float* __restrict__ kern,
                           const float* __restrict__ bias,
                           float* __restrict__ WTj) {
    int idx = blockIdx.x * 256 + threadIdx.x;
    if (idx >= 32 * SW) return;
    int j = idx / SW;
    int r = idx - j * SW;
    int b = r >> 5, i = r & 31;
    WTj[idx] = (b < BD) ? kern[b * 1024 + i * 32 + j] : bias[i * 32 + j];
}

// CSR by SRC (pair[:,1])
__global__ void k_hist(const int* __restrict__ pair, int* __restrict__ deg) {
    int e = blockIdx.x * 256 + threadIdx.x;
    if (e < E_EDGES) atomicAdd(&deg[pair[2 * e + 1]], 1);
}

__global__ void k_scan1(const int* __restrict__ deg, int* __restrict__ offs,
                        int* __restrict__ bsums) {
    __shared__ int sm[256];
    int t = threadIdx.x, gid = blockIdx.x * 256 + t;
    int v = deg[gid];                 // deg[50000..PADN) is zeroed
    sm[t] = v;
    __syncthreads();
    for (int off = 1; off < 256; off <<= 1) {
        int x = (t >= off) ? sm[t - off] : 0;
        __syncthreads();
        sm[t] += x;
        __syncthreads();
    }
    offs[gid] = sm[t] - v;
    if (t == 255) bsums[blockIdx.x] = sm[255];
}

__global__ void k_scan2(const int* __restrict__ bsums, int* __restrict__ boffs, int nb) {
    __shared__ int sm[256];
    int t = threadIdx.x;
    int v = (t < nb) ? bsums[t] : 0;
    sm[t] = v;
    __syncthreads();
    for (int off = 1; off < 256; off <<= 1) {
        int x = (t >= off) ? sm[t - off] : 0;
        __syncthreads();
        sm[t] += x;
        __syncthreads();
    }
    if (t < nb) boffs[t] = sm[t] - v;
}

__global__ void k_scan3(int* __restrict__ offs, const int* __restrict__ boffs) {
    int gid = blockIdx.x * 256 + threadIdx.x;
    offs[gid] += boffs[blockIdx.x];
}

// Permute edges to src-CSR order; materialize bond rows and dst in that order.
__global__ void k_scatter_perm(const int* __restrict__ pair, const int* __restrict__ offs,
                               int* __restrict__ cursor, const float* __restrict__ bond,
                               float* __restrict__ bond_perm, int* __restrict__ dstid) {
    int e = blockIdx.x * 256 + threadIdx.x;
    if (e >= E_EDGES) return;
    int d = pair[2 * e], s = pair[2 * e + 1];
    int pos = offs[s] + atomicAdd(&cursor[s], 1);
    dstid[pos] = d;
    const float4* src4 = (const float4*)(bond + (size_t)e * BD);
    float4* dst4 = (float4*)(bond_perm + (size_t)pos * BD);
    dst4[0] = src4[0];
    dst4[1] = src4[1];
    dst4[2] = src4[2];
    dst4[3] = src4[3];
}

#define EDGE_FMA(M, B0, B1, B2, B3, YN) do {            \
    M = fmaf(B0.x, YN[0],  M); M = fmaf(B0.y, YN[1],  M); \
    M = fmaf(B0.z, YN[2],  M); M = fmaf(B0.w, YN[3],  M); \
    M = fmaf(B1.x, YN[4],  M); M = fmaf(B1.y, YN[5],  M); \
    M = fmaf(B1.z, YN[6],  M); M = fmaf(B1.w, YN[7],  M); \
    M = fmaf(B2.x, YN[8],  M); M = fmaf(B2.y, YN[9],  M); \
    M = fmaf(B2.z, YN[10], M); M = fmaf(B2.w, YN[11], M); \
    M = fmaf(B3.x, YN[12], M); M = fmaf(B3.y, YN[13], M); \
    M = fmaf(B3.z, YN[14], M); M = fmaf(B3.w, YN[15], M); \
} while (0)

#define LOAD_WV(WVA, JJ) do {                           \
    _Pragma("unroll")                                   \
    for (int b = 0; b < 17; ++b)                        \
        WVA[b] = WTj[(JJ) * SW + b * 32 + i];           \
} while (0)

#define FMA_WV(WVA, JJ) do {                            \
    _Pragma("unroll")                                   \
    for (int n = 0; n < 4; ++n) {                       \
        const float hv = h_lds[hn0 + n][(JJ)];          \
        _Pragma("unroll")                               \
        for (int b = 0; b < 17; ++b)                    \
            y[n][b] = fmaf(WVA[b], hv, y[n][b]);        \
    }                                                   \
} while (0)

// ---------- fused projection + edge kernel (r17 config: session best) ----------
// Phase A j-loop unrolled x2 with two named wv buffers (software pipeline);
// (256,2) is the only no-spill config for this body (compiler parks y[4][17]
// in the unified AGPR file: 72 VGPR / SGPR 32 / zero scratch). Do NOT raise
// the occupancy floor (r18/r19: both spill catastrophically).
__global__ __launch_bounds__(256, 2)
void k_fused(const float* __restrict__ h_in, float* __restrict__ agg,
             const float* __restrict__ bond_perm, const int* __restrict__ dstid,
             const float* __restrict__ WTj,
             const int* __restrict__ offs, const int* __restrict__ deg) {
    __shared__ float h_lds[NB][33];       // 4224 B

    const int t = threadIdx.x;
    const int bbase = blockIdx.x * NB;
    const int i = t & 31;                 // feature lane
    const int grp = t >> 5;               // half-wave 0..7
    const int hn0 = grp * 4;

    // ---- stage h tile (coalesced, guarded)
#pragma unroll
    for (int k = 0; k < 4; ++k) {
        const int idx = t + 256 * k;
        const int n = idx >> 5, j = idx & 31;
        const int node = bbase + n;
        h_lds[n][j] = (node < N_ATOMS) ? h_in[(size_t)node * D + j] : 0.f;
    }

    int stv[4], env[4];
#pragma unroll
    for (int n = 0; n < 4; ++n) {
        const int node = bbase + hn0 + n;
        const bool ok = (node < N_ATOMS);
        const int o = ok ? offs[node] : 0;
        stv[n] = o;
        env[n] = o + (ok ? deg[node] : 0);
    }
    __syncthreads();

    // ---- Phase A: y[n][b] = sum_j WTj[j][b*32+i] * h[node_n][j], sw-pipelined
    float y[4][17];
#pragma unroll
    for (int n = 0; n < 4; ++n)
#pragma unroll
        for (int b = 0; b < 17; ++b) y[n][b] = 0.f;

    {
        float wvA[17], wvB[17];
        LOAD_WV(wvA, 0);                  // prologue: j=0 in flight
        for (int j = 0; j < 32; j += 2) { // 16 iters, each: load-next, fma-cur
            LOAD_WV(wvB, j + 1);          // issue j+1 loads BEFORE j's FMAs
            FMA_WV(wvA, j);
            if (j + 2 < 32) LOAD_WV(wvA, j + 2);
            FMA_WV(wvB, j + 1);
        }
    }

    // ---- Phase B: linear streams in, fire-and-forget atomics out
#pragma unroll
    for (int n = 0; n < 4; ++n) {
        int p = stv[n];
        const int e = env[n];
        for (; p + 2 <= e; p += 2) {
            const float4* bp0 = (const float4*)(bond_perm + (size_t)p * BD);
            const float4* bp1 = (const float4*)(bond_perm + (size_t)(p + 1) * BD);
            const int d0 = dstid[p];
            const int d1 = dstid[p + 1];
            const float4 a0 = bp0[0], a1 = bp0[1], a2 = bp0[2], a3 = bp0[3];
            const float4 c0 = bp1[0], c1 = bp1[1], c2 = bp1[2], c3 = bp1[3];
            float m0 = y[n][16];          // bias channel (bond == 1)
            float m1 = y[n][16];
            EDGE_FMA(m0, a0, a1, a2, a3, y[n]);
            EDGE_FMA(m1, c0, c1, c2, c3, y[n]);
            atomicAdd(&agg[(size_t)d0 * D + i], m0);
            atomicAdd(&agg[(size_t)d1 * D + i], m1);
        }
        if (p < e) {
            const float4* bp0 = (const float4*)(bond_perm + (size_t)p * BD);
            const int d0 = dstid[p];
            const float4 a0 = bp0[0], a1 = bp0[1], a2 = bp0[2], a3 = bp0[3];
            float m0 = y[n][16];
            EDGE_FMA(m0, a0, a1, a2, a3, y[n]);
            atomicAdd(&agg[(size_t)d0 * D + i], m0);
        }
    }
}

// ---------- GRU kernel: h_out = GRUCell(agg, h_in); zeroes agg after read ----------
__global__ __launch_bounds__(256, 2)
void k_gru(float* __restrict__ agg_g, const float* __restrict__ h_in,
           float* __restrict__ h_out,
           const float* __restrict__ Wih, const float* __restrict__ Whh,
           const float* __restrict__ bih, const float* __restrict__ bhh) {
    __shared__ float Wih_s[96][33];
    __shared__ float Whh_s[96][33];
    __shared__ float bih_s[96], bhh_s[96];
    __shared__ float x_lds[GRU_TILE][32];
    __shared__ float h_lds[GRU_TILE][32];

    const int t = threadIdx.x;

    for (int idx = t; idx < 96 * 32; idx += 256) {
        const int o = idx >> 5, jj = idx & 31;
        Wih_s[o][jj] = Wih[idx];
        Whh_s[o][jj] = Whh[idx];
    }
    if (t < 96) { bih_s[t] = bih[t]; bhh_s[t] = bhh[t]; }

    const int r = t >> 5;
    const int i = t & 31;
    const int stride = gridDim.x;

    int tile = blockIdx.x;
    float xr = 0.f, hr = 0.f;
    if (tile < GRU_NT) {
        xr = agg_g[tile * 256 + t];
        hr = h_in[tile * 256 + t];
    }
    for (; tile < GRU_NT; tile += stride) {
        ((float*)x_lds)[t] = xr;
        ((float*)h_lds)[t] = hr;
        agg_g[tile * 256 + t] = 0.f;      // consumed -> zero for next step
        __syncthreads();
        const int nxt = tile + stride;
        if (nxt < GRU_NT) {               // prefetch next tile during compute
            xr = agg_g[nxt * 256 + t];
            hr = h_in[nxt * 256 + t];
        }
        float gri = bih_s[i],      grh = bhh_s[i];
        float gzi = bih_s[32 + i], gzh = bhh_s[32 + i];
        float gni = bih_s[64 + i], gnh = bhh_s[64 + i];
#pragma unroll 8
        for (int jj = 0; jj < 32; ++jj) {
            const float xv = x_lds[r][jj];
            const float hv = h_lds[r][jj];
            gri = fmaf(Wih_s[i][jj],      xv, gri);
            gzi = fmaf(Wih_s[32 + i][jj], xv, gzi);
            gni = fmaf(Wih_s[64 + i][jj], xv, gni);
            grh = fmaf(Whh_s[i][jj],      hv, grh);
            gzh = fmaf(Whh_s[32 + i][jj], hv, gzh);
            gnh = fmaf(Whh_s[64 + i][jj], hv, gnh);
        }
        const float rg = sigmoidf_(gri + grh);
        const float zg = sigmoidf_(gzi + gzh);
        float xn = gni + rg * gnh;
        xn = fminf(fmaxf(xn, -15.f), 15.f);
        const float e2 = __expf(2.f * xn);
        const float ng = (e2 - 1.f) / (e2 + 1.f);
        h_out[tile * 256 + t] = (1.f - zg) * ng + zg * h_lds[r][i];
        __syncthreads();
    }
}

// ---------- launch ----------
extern "C" void kernel_launch(void* const* d_in, const int* in_sizes, int n_in,
                              void* d_out, int out_size, void* d_ws, size_t ws_size,
                              hipStream_t stream) {
    const float* atom = (const float*)d_in[0];
    const float* bond = (const float*)d_in[1];
    const int*   pair = (const int*)d_in[2];
    const float* kern = (const float*)d_in[3];
    const float* bias = (const float*)d_in[4];
    const float* Wih  = (const float*)d_in[5];
    const float* Whh  = (const float*)d_in[6];
    const float* bih  = (const float*)d_in[7];
    const float* bhh  = (const float*)d_in[8];
    float* out = (float*)d_out;

    char* w = (char*)d_ws;
    auto alloc = [&](size_t bytes) {
        char* p = w;
        w += (bytes + 255) & ~size_t(255);
        return p;
    };
    float* hA        = (float*)alloc((size_t)N_ATOMS * D * 4);
    float* aggG      = (float*)alloc((size_t)N_ATOMS * D * 4);
    float* WTj       = (float*)alloc((size_t)32 * SW * 4);
    int*   degcur    = (int*)alloc((size_t)2 * PADN * 4);   // deg | cursor
    int*   offs      = (int*)alloc((size_t)PADN * 4);
    int*   bsums     = (int*)alloc(256 * 4);
    int*   boffs     = (int*)alloc(256 * 4);
    int*   dstid     = (int*)alloc((size_t)E_EDGES * 4);
    float* bond_perm = (float*)alloc((size_t)E_EDGES * BD * 4);
    int* deg    = degcur;
    int* cursor = degcur + PADN;

    hipMemsetAsync(degcur, 0, (size_t)2 * PADN * 4, stream);
    hipMemsetAsync(aggG, 0, (size_t)N_ATOMS * D * 4, stream);  // k_gru re-zeroes thereafter

    k_build_wt<<<(32 * SW + 255) / 256, 256, 0, stream>>>(kern, bias, WTj);
    k_hist<<<(E_EDGES + 255) / 256, 256, 0, stream>>>(pair, deg);
    k_scan1<<<SCAN_BLOCKS, 256, 0, stream>>>(deg, offs, bsums);
    k_scan2<<<1, 256, 0, stream>>>(bsums, boffs, SCAN_BLOCKS);
    k_scan3<<<SCAN_BLOCKS, 256, 0, stream>>>(offs, boffs);
    k_scatter_perm<<<(E_EDGES + 255) / 256, 256, 0, stream>>>(pair, offs, cursor,
                                                              bond, bond_perm, dstid);

    const float* hsrc = atom;
    float* hdst[4] = { hA, out, hA, out };
    for (int s = 0; s < 4; ++s) {
        k_fused<<<FBLOCKS, 256, 0, stream>>>(hsrc, aggG, bond_perm, dstid,
                                             WTj, offs, deg);
        k_gru<<<1024, 256, 0, stream>>>(aggG, hsrc, hdst[s], Wih, Whh, bih, bhh);
        hsrc = hdst[s];
    }
}